// Round 1
// baseline (3132.407 us; speedup 1.0000x reference)
//
#include <hip/hip_runtime.h>
#include <math.h>

typedef unsigned int uint32;
typedef unsigned short ushort16;

#define CIN 128
#define HID 256
#define COUT 40
#define KPROP 10
#define ONE_MINUS_ALPHA 0.95f
#define PPR_ALPHA 0.05f
#define SCAN_CHUNK 1024
#define BM 32

// ---------------- CSR build ----------------

__global__ void hist_kernel(const int* __restrict__ src, int* __restrict__ cnt, int E) {
  int i = blockIdx.x * blockDim.x + threadIdx.x;
  int stride = gridDim.x * blockDim.x;
  for (; i < E; i += stride) atomicAdd(&cnt[src[i]], 1);
}

__global__ void chunk_sum_kernel(const int* __restrict__ cnt, int* __restrict__ bsum, int n) {
  __shared__ int smem[256];
  int b = blockIdx.x, t = threadIdx.x;
  int base = b * SCAN_CHUNK;
  int s = 0;
  for (int k = 0; k < 4; ++k) {
    int idx = base + t + k * 256;
    if (idx < n) s += cnt[idx];
  }
  smem[t] = s;
  __syncthreads();
  for (int off = 128; off > 0; off >>= 1) {
    if (t < off) smem[t] += smem[t + off];
    __syncthreads();
  }
  if (t == 0) bsum[b] = smem[0];
}

__global__ void bsum_scan_kernel(int* bsum, int nb) {
  if (threadIdx.x == 0 && blockIdx.x == 0) {
    int run = 0;
    for (int i = 0; i < nb; ++i) { int v = bsum[i]; bsum[i] = run; run += v; }
  }
}

__global__ void chunk_scan_kernel(const int* __restrict__ cnt, const int* __restrict__ bsum,
                                  int* __restrict__ rowptr, int n) {
  __shared__ int smem[256];
  int b = blockIdx.x, t = threadIdx.x;
  int base = b * SCAN_CHUNK + t * 4;
  int v[4];
  for (int k = 0; k < 4; ++k) v[k] = (base + k < n) ? cnt[base + k] : 0;
  int s = v[0] + v[1] + v[2] + v[3];
  smem[t] = s;
  __syncthreads();
  // inclusive Hillis-Steele over thread sums
  for (int off = 1; off < 256; off <<= 1) {
    int add = (t >= off) ? smem[t - off] : 0;
    __syncthreads();
    smem[t] += add;
    __syncthreads();
  }
  int run = bsum[b] + smem[t] - s;  // exclusive offset for this thread's first element
  for (int k = 0; k < 4; ++k) {
    run += v[k];
    if (base + k < n) rowptr[base + k + 1] = run;
  }
  if (b == 0 && t == 0) rowptr[0] = 0;
}

__global__ void scatter_kernel(const int* __restrict__ src, const int* __restrict__ dst,
                               int* __restrict__ cursor, int* __restrict__ cols, int E) {
  int i = blockIdx.x * blockDim.x + threadIdx.x;
  int stride = gridDim.x * blockDim.x;
  for (; i < E; i += stride) {
    int pos = atomicAdd(&cursor[src[i]], 1);
    cols[pos] = dst[i];
  }
}

__global__ void transpose_w1_kernel(const float* __restrict__ W1, float* __restrict__ W1T) {
  int idx = blockIdx.x * blockDim.x + threadIdx.x;
  if (idx < HID * CIN) {
    int j = idx / CIN;   // hidden unit (row of W1)
    int c = idx % CIN;   // input channel
    W1T[c * HID + j] = W1[idx];
  }
}

// ---------------- propagation: uout = x + 0.95 * D^-1 * (A u + u_self) ----------------

__global__ __launch_bounds__(256) void prop_kernel(
    const float* __restrict__ uin, const float* __restrict__ x, float* __restrict__ uout,
    const int* __restrict__ rowptr, const int* __restrict__ cols, int n) {
  int wid = threadIdx.x >> 6;
  int lane = threadIdx.x & 63;
  int node = blockIdx.x * 4 + wid;
  if (node >= n) return;
  int start = rowptr[node], end = rowptr[node + 1];
  const float2* uin2 = (const float2*)uin;
  // self loop contribution
  float2 self = uin2[(size_t)node * 64 + lane];
  float2 a0 = self, a1 = {0.f, 0.f}, a2 = {0.f, 0.f}, a3 = {0.f, 0.f};
  int e = start;
  for (; e + 4 <= end; e += 4) {
    int d0 = cols[e + 0];
    int d1 = cols[e + 1];
    int d2 = cols[e + 2];
    int d3 = cols[e + 3];
    float2 v0 = uin2[(size_t)d0 * 64 + lane];
    float2 v1 = uin2[(size_t)d1 * 64 + lane];
    float2 v2 = uin2[(size_t)d2 * 64 + lane];
    float2 v3 = uin2[(size_t)d3 * 64 + lane];
    a0.x += v0.x; a0.y += v0.y;
    a1.x += v1.x; a1.y += v1.y;
    a2.x += v2.x; a2.y += v2.y;
    a3.x += v3.x; a3.y += v3.y;
  }
  for (; e < end; ++e) {
    int d = cols[e];
    float2 v = uin2[(size_t)d * 64 + lane];
    a0.x += v.x; a0.y += v.y;
  }
  float sx = (a0.x + a1.x) + (a2.x + a3.x);
  float sy = (a0.y + a1.y) + (a2.y + a3.y);
  float dinv = 1.0f / (float)(end - start + 1);
  float2 xs = ((const float2*)x)[(size_t)node * 64 + lane];
  float2 r;
  r.x = xs.x + ONE_MINUS_ALPHA * dinv * sx;
  r.y = xs.y + ONE_MINUS_ALPHA * dinv * sy;
  ((float2*)uout)[(size_t)node * 64 + lane] = r;
}

// ---------------- fused MLP + log_softmax ----------------
// block = 128 threads (2 waves), BM = 32 nodes per block.
// LDS: regionA (accS f32 [32][128] 16KB, later W2T bf16 [256][40] 20KB) +
//      hS f32 [32][260] 33.3KB + outS [32][40] 5KB + mx/l  -> ~59KB

__device__ inline ushort16 f32_to_bf16_bits(float f) {
  uint32 u = __float_as_uint(f);
  u += 0x7fffu + ((u >> 16) & 1u);
  return (ushort16)(u >> 16);
}

__global__ __launch_bounds__(128) void mlp_kernel(
    const float* __restrict__ uK, const float* __restrict__ W1T,
    const float* __restrict__ b1, const float* __restrict__ W2,
    const float* __restrict__ b2, float* __restrict__ out, int n) {
  __shared__ __align__(16) float regionA[HID * COUT / 2];  // 5120 floats = 20480 B
  __shared__ __align__(16) float hS[BM][260];
  __shared__ float outS[BM][COUT];
  __shared__ float mxS[BM], lS[BM];

  int t = threadIdx.x;
  int node0 = blockIdx.x * BM;

  // ---- phase 1: stage acc = ALPHA * uK tile into regionA as [32][128] f32 ----
  {
    float* accS = regionA;  // 4096 floats = 16384 B, fits in 20480
    for (int r = 0; r < 32; ++r) {
      int idx = r * 128 + t;
      int m = idx >> 7, c = idx & 127;
      float v = 0.f;
      if (node0 + m < n) v = PPR_ALPHA * uK[(size_t)(node0 + m) * CIN + c];
      accS[m * CIN + c] = v;
    }
  }
  __syncthreads();

  // ---- phase 2: mm1  h[m][j] = relu(b1[j] + sum_c acc[m][c] * W1[j][c]) ----
  {
    const float4* accS4 = (const float4*)regionA;  // [32][32] float4
    int j0 = t, j1 = t + 128;
    float h0[BM], h1[BM];
    float bb0 = b1[j0], bb1 = b1[j1];
#pragma unroll
    for (int m = 0; m < BM; ++m) { h0[m] = bb0; h1[m] = bb1; }
    for (int c4 = 0; c4 < 32; ++c4) {
      int c = c4 * 4;
      float w00 = W1T[(c + 0) * HID + j0];
      float w10 = W1T[(c + 1) * HID + j0];
      float w20 = W1T[(c + 2) * HID + j0];
      float w30 = W1T[(c + 3) * HID + j0];
      float w01 = W1T[(c + 0) * HID + j1];
      float w11 = W1T[(c + 1) * HID + j1];
      float w21 = W1T[(c + 2) * HID + j1];
      float w31 = W1T[(c + 3) * HID + j1];
#pragma unroll
      for (int m = 0; m < BM; ++m) {
        float4 a = accS4[m * 32 + c4];
        h0[m] = fmaf(a.x, w00, h0[m]);
        h0[m] = fmaf(a.y, w10, h0[m]);
        h0[m] = fmaf(a.z, w20, h0[m]);
        h0[m] = fmaf(a.w, w30, h0[m]);
        h1[m] = fmaf(a.x, w01, h1[m]);
        h1[m] = fmaf(a.y, w11, h1[m]);
        h1[m] = fmaf(a.z, w21, h1[m]);
        h1[m] = fmaf(a.w, w31, h1[m]);
      }
    }
#pragma unroll
    for (int m = 0; m < BM; ++m) {
      hS[m][j0] = fmaxf(h0[m], 0.f);
      hS[m][j1] = fmaxf(h1[m], 0.f);
    }
  }
  __syncthreads();  // all accS reads done, hS complete

  // ---- phase 3: stage W2T (bf16) into regionA as [256][40]: W2T[j][o] = W2[o][j] ----
  {
    ushort16* W2T = (ushort16*)regionA;
    for (int r = 0; r < 80; ++r) {
      int idx = r * 128 + t;  // 10240 elements
      int j = idx / COUT, o = idx % COUT;
      W2T[idx] = f32_to_bf16_bits(W2[o * HID + j]);
    }
  }
  __syncthreads();

  // ---- phase 4: mm2  out[m][o] = b2[o] + sum_j h[m][j] * W2[o][j], split over j-halves ----
  {
    const ushort16* W2T = (const ushort16*)regionA;
    int o = t & 63;
    int half = t >> 6;          // wave 0: half 0 (j 0..127), wave 1: half 1 (j 128..255)
    int oc = (o < COUT) ? o : (COUT - 1);
    float part[BM];
#pragma unroll
    for (int m = 0; m < BM; ++m) part[m] = 0.f;
    int jbase = half * 128;
    for (int js = 0; js < 128; js += 4) {
      int j = jbase + js;
      float w0 = __uint_as_float((uint32)W2T[(j + 0) * COUT + oc] << 16);
      float w1 = __uint_as_float((uint32)W2T[(j + 1) * COUT + oc] << 16);
      float w2 = __uint_as_float((uint32)W2T[(j + 2) * COUT + oc] << 16);
      float w3 = __uint_as_float((uint32)W2T[(j + 3) * COUT + oc] << 16);
#pragma unroll
      for (int m = 0; m < BM; ++m) {
        float4 hv = *(const float4*)&hS[m][j];
        part[m] = fmaf(hv.x, w0, part[m]);
        part[m] = fmaf(hv.y, w1, part[m]);
        part[m] = fmaf(hv.z, w2, part[m]);
        part[m] = fmaf(hv.w, w3, part[m]);
      }
    }
    if (half == 0 && o < COUT) {
      float bb = b2[o];
#pragma unroll
      for (int m = 0; m < BM; ++m) outS[m][o] = bb + part[m];
    }
    __syncthreads();
    if (half == 1 && o < COUT) {
#pragma unroll
      for (int m = 0; m < BM; ++m) outS[m][o] += part[m];
    }
  }
  __syncthreads();

  // ---- phase 5: log_softmax ----
  if (t < BM) {
    int m = t;
    float mx = -INFINITY;
    for (int o = 0; o < COUT; ++o) mx = fmaxf(mx, outS[m][o]);
    float s = 0.f;
    for (int o = 0; o < COUT; ++o) s += __expf(outS[m][o] - mx);
    mxS[m] = mx;
    lS[m] = __logf(s);
  }
  __syncthreads();
  for (int r = 0; r < 10; ++r) {
    int idx = r * 128 + t;  // 1280 outputs
    int m = idx / COUT, o = idx % COUT;
    int node = node0 + m;
    if (node < n) out[(size_t)node * COUT + o] = outS[m][o] - mxS[m] - lS[m];
  }
}

// ---------------- launch ----------------

extern "C" void kernel_launch(void* const* d_in, const int* in_sizes, int n_in,
                              void* d_out, int out_size, void* d_ws, size_t ws_size,
                              hipStream_t stream) {
  const float* x = (const float*)d_in[0];
  const int* ei = (const int*)d_in[1];
  const float* W1 = (const float*)d_in[3];
  const float* b1 = (const float*)d_in[4];
  const float* W2 = (const float*)d_in[5];
  const float* b2 = (const float*)d_in[6];
  float* out = (float*)d_out;

  int N = in_sizes[0] / CIN;
  int E = in_sizes[1] / 2;
  const int* src = ei;        // edge_index[0] = rows of A
  const int* dst = ei + E;    // edge_index[1] = cols of A

  char* ws = (char*)d_ws;
  size_t off = 0;
  auto walloc = [&](size_t bytes) -> void* {
    void* p = ws + off;
    off += (bytes + 255) & ~(size_t)255;
    return p;
  };
  int* cnt = (int*)walloc((size_t)N * 4);
  int* rowptr = (int*)walloc(((size_t)N + 1) * 4);
  int* cursor = (int*)walloc((size_t)N * 4);
  int* bsum = (int*)walloc(1024 * 4);
  int* cols = (int*)walloc((size_t)E * 4);
  float* W1T = (float*)walloc((size_t)CIN * HID * 4);
  float* u0 = (float*)walloc((size_t)N * CIN * 4);
  float* u1 = (float*)walloc((size_t)N * CIN * 4);
  (void)ws_size; (void)n_in; (void)out_size;

  // CSR build (counting sort by src)
  hipMemsetAsync(cnt, 0, (size_t)N * 4, stream);
  hist_kernel<<<2048, 256, 0, stream>>>(src, cnt, E);
  int nchunks = (N + SCAN_CHUNK - 1) / SCAN_CHUNK;
  chunk_sum_kernel<<<nchunks, 256, 0, stream>>>(cnt, bsum, N);
  bsum_scan_kernel<<<1, 64, 0, stream>>>(bsum, nchunks);
  chunk_scan_kernel<<<nchunks, 256, 0, stream>>>(cnt, bsum, rowptr, N);
  hipMemcpyAsync(cursor, rowptr, (size_t)N * 4, hipMemcpyDeviceToDevice, stream);
  scatter_kernel<<<2048, 256, 0, stream>>>(src, dst, cursor, cols, E);
  transpose_w1_kernel<<<(HID * CIN + 255) / 256, 256, 0, stream>>>(W1, W1T);

  // Horner PPR: u <- x + 0.95 * P u   (10 times), acc = 0.05 * u_final
  const float* uin = x;
  float* ubufs[2] = {u0, u1};
  for (int k = 0; k < KPROP; ++k) {
    float* uout = ubufs[k & 1];
    prop_kernel<<<(N + 3) / 4, 256, 0, stream>>>(uin, x, uout, rowptr, cols, N);
    uin = uout;
  }

  mlp_kernel<<<(N + BM - 1) / BM, 128, 0, stream>>>(uin, W1T, b1, W2, b2, out, N);
}

// Round 2
// 1750.680 us; speedup vs baseline: 1.7893x; 1.7893x over previous
//
#include <hip/hip_runtime.h>
#include <math.h>

typedef unsigned int uint32;
typedef unsigned short u16;
typedef __attribute__((ext_vector_type(8))) short short8;
typedef __attribute__((ext_vector_type(4))) float float4v;

#define CIN 128
#define HID 256
#define COUT 40
#define KPROP 10
#define ONE_MINUS_ALPHA 0.95f
#define PPR_ALPHA 0.05f
#define SCAN_CHUNK 1024

__device__ inline u16 f2bf(float f) {
  uint32 u = __float_as_uint(f);
  u += 0x7fffu + ((u >> 16) & 1u);
  return (u16)(u >> 16);
}
__device__ inline float bflo(uint32 w) { return __uint_as_float(w << 16); }
__device__ inline float bfhi(uint32 w) { return __uint_as_float(w & 0xffff0000u); }

// ---------------- CSR build ----------------

__global__ void hist_kernel(const int* __restrict__ src, int* __restrict__ cnt, int E) {
  int i = blockIdx.x * blockDim.x + threadIdx.x;
  int stride = gridDim.x * blockDim.x;
  for (; i < E; i += stride) atomicAdd(&cnt[src[i]], 1);
}

__global__ void chunk_sum_kernel(const int* __restrict__ cnt, int* __restrict__ bsum, int n) {
  __shared__ int smem[256];
  int b = blockIdx.x, t = threadIdx.x;
  int base = b * SCAN_CHUNK;
  int s = 0;
  for (int k = 0; k < 4; ++k) {
    int idx = base + t + k * 256;
    if (idx < n) s += cnt[idx];
  }
  smem[t] = s;
  __syncthreads();
  for (int off = 128; off > 0; off >>= 1) {
    if (t < off) smem[t] += smem[t + off];
    __syncthreads();
  }
  if (t == 0) bsum[b] = smem[0];
}

__global__ void bsum_scan_kernel(int* bsum, int nb) {
  if (threadIdx.x == 0 && blockIdx.x == 0) {
    int run = 0;
    for (int i = 0; i < nb; ++i) { int v = bsum[i]; bsum[i] = run; run += v; }
  }
}

__global__ void chunk_scan_kernel(const int* __restrict__ cnt, const int* __restrict__ bsum,
                                  int* __restrict__ rowptr, int n) {
  __shared__ int smem[256];
  int b = blockIdx.x, t = threadIdx.x;
  int base = b * SCAN_CHUNK + t * 4;
  int v[4];
  for (int k = 0; k < 4; ++k) v[k] = (base + k < n) ? cnt[base + k] : 0;
  int s = v[0] + v[1] + v[2] + v[3];
  smem[t] = s;
  __syncthreads();
  for (int off = 1; off < 256; off <<= 1) {
    int add = (t >= off) ? smem[t - off] : 0;
    __syncthreads();
    smem[t] += add;
    __syncthreads();
  }
  int run = bsum[b] + smem[t] - s;
  for (int k = 0; k < 4; ++k) {
    run += v[k];
    if (base + k < n) rowptr[base + k + 1] = run;
  }
  if (b == 0 && t == 0) rowptr[0] = 0;
}

__global__ void scatter_kernel(const int* __restrict__ src, const int* __restrict__ dst,
                               int* __restrict__ cursor, int* __restrict__ cols, int E) {
  int i = blockIdx.x * blockDim.x + threadIdx.x;
  int stride = gridDim.x * blockDim.x;
  for (; i < E; i += stride) {
    int pos = atomicAdd(&cursor[src[i]], 1);
    cols[pos] = dst[i];
  }
}

// ---------------- prep: casts + weight packing ----------------

__global__ void cvt_bf16_kernel(const float* __restrict__ in, u16* __restrict__ out, int n4) {
  int i = blockIdx.x * blockDim.x + threadIdx.x;
  if (i < n4) {
    float4 v = ((const float4*)in)[i];
    uint2 p;
    p.x = (uint32)f2bf(v.x) | ((uint32)f2bf(v.y) << 16);
    p.y = (uint32)f2bf(v.z) | ((uint32)f2bf(v.w) << 16);
    ((uint2*)out)[i] = p;
  }
}

// W1P: B-fragment packed, 0.05 folded in. idx = ((kk*16+nt)*64+l)*8+j8
// element = 0.05 * W1T[k][n],  k = kk*32 + (l>>4)*8 + j8,  n = nt*16 + (l&15)
// W1 is [HID][CIN] row-major; W1T[k][n] = W1[n*CIN + k]
__global__ void pack_w1_kernel(const float* __restrict__ W1, u16* __restrict__ W1P) {
  int idx = blockIdx.x * blockDim.x + threadIdx.x;
  if (idx >= 4 * 16 * 64 * 8) return;
  int j8 = idx & 7;
  int l = (idx >> 3) & 63;
  int nt = (idx >> 9) & 15;
  int kk = idx >> 13;
  int k = kk * 32 + (l >> 4) * 8 + j8;
  int nn = nt * 16 + (l & 15);
  W1P[idx] = f2bf(PPR_ALPHA * W1[nn * CIN + k]);
}

// W2P: idx = ((kk2*3+nt2)*64+l)*8+j8 ; k = kk2*32+(l>>4)*8+j8 ; o = nt2*16+(l&15)
// element = W2[o][k] = W2[o*HID+k], zero-padded for o>=40
__global__ void pack_w2_kernel(const float* __restrict__ W2, u16* __restrict__ W2P) {
  int idx = blockIdx.x * blockDim.x + threadIdx.x;
  if (idx >= 8 * 3 * 64 * 8) return;
  int j8 = idx & 7;
  int l = (idx >> 3) & 63;
  int nt2 = (idx >> 9) % 3;
  int kk2 = (idx >> 9) / 3;
  int k = kk2 * 32 + (l >> 4) * 8 + j8;
  int o = nt2 * 16 + (l & 15);
  W2P[idx] = (o < COUT) ? f2bf(W2[o * HID + k]) : (u16)0;
}

// ---------------- propagation (bf16): uout = bf16( x + 0.95 * D^-1 * (A u + u) ) ----------------
// wave per node; lane handles 2 channels (one uint32 = ushort2 of bf16).

__global__ __launch_bounds__(256) void prop_bf16_kernel(
    const u16* __restrict__ uin, const u16* __restrict__ xb, u16* __restrict__ uout,
    const int* __restrict__ rowptr, const int* __restrict__ cols, int n) {
  int wid = threadIdx.x >> 6;
  int lane = threadIdx.x & 63;
  int node = blockIdx.x * 4 + wid;
  if (node >= n) return;
  int start = rowptr[node], end = rowptr[node + 1];
  const uint32* uw = (const uint32*)uin;
  uint32 selfw = uw[(size_t)node * 64 + lane];
  float a0x = bflo(selfw), a0y = bfhi(selfw);
  float a1x = 0.f, a1y = 0.f, a2x = 0.f, a2y = 0.f, a3x = 0.f, a3y = 0.f;
  int e = start;
  for (; e + 4 <= end; e += 4) {
    int d0 = cols[e + 0];
    int d1 = cols[e + 1];
    int d2 = cols[e + 2];
    int d3 = cols[e + 3];
    uint32 w0 = uw[(size_t)d0 * 64 + lane];
    uint32 w1 = uw[(size_t)d1 * 64 + lane];
    uint32 w2 = uw[(size_t)d2 * 64 + lane];
    uint32 w3 = uw[(size_t)d3 * 64 + lane];
    a0x += bflo(w0); a0y += bfhi(w0);
    a1x += bflo(w1); a1y += bfhi(w1);
    a2x += bflo(w2); a2y += bfhi(w2);
    a3x += bflo(w3); a3y += bfhi(w3);
  }
  for (; e < end; ++e) {
    uint32 w0 = uw[(size_t)cols[e] * 64 + lane];
    a0x += bflo(w0); a0y += bfhi(w0);
  }
  float sx = (a0x + a1x) + (a2x + a3x);
  float sy = (a0y + a1y) + (a2y + a3y);
  float dinv = 1.0f / (float)(end - start + 1);
  uint32 xw = ((const uint32*)xb)[(size_t)node * 64 + lane];
  float rx = bflo(xw) + ONE_MINUS_ALPHA * dinv * sx;
  float ry = bfhi(xw) + ONE_MINUS_ALPHA * dinv * sy;
  ((uint32*)uout)[(size_t)node * 64 + lane] = (uint32)f2bf(rx) | ((uint32)f2bf(ry) << 16);
}

// ---------------- fused MFMA MLP + log_softmax ----------------
// block = 256 threads (4 waves); each wave owns 32 rows (2 m-tiles of 16).
// mm1: h = relu(u @ (0.05*W1T) + b1), bf16 MFMA 16x16x32, A direct from global.
// h round-trips C-layout -> LDS (padded) -> A-layout for mm2.
// mm2: out = h @ W2T + b2, then per-row log_softmax via 16-lane shuffles.

#define HPAD 264  // 264 u16 = 528 B row stride; 132 dw % 32 = 4 -> 2-way (free)

__global__ __launch_bounds__(256, 2) void mlp_mfma_kernel(
    const u16* __restrict__ u, const u16* __restrict__ W1P, const float* __restrict__ b1,
    const u16* __restrict__ W2P, const float* __restrict__ b2,
    float* __restrict__ out, int n) {
  __shared__ __align__(16) u16 hS[128][HPAD];  // 67584 B

  int t = threadIdx.x;
  int w = t >> 6, l = t & 63;
  int lg = l >> 4;   // k-group (A/B) or row-group (C)
  int ln = l & 15;   // m (A) / n (B,C)
  int node0 = blockIdx.x * 128;

  // ---- A fragments for mm1: u[node][kk*32 + lg*8 .. +8], 2 m-tiles ----
  short8 a1[2][4];
#pragma unroll
  for (int mt = 0; mt < 2; ++mt) {
    int node = node0 + w * 32 + mt * 16 + ln;
    if (node >= n) node = n - 1;
    const short8* urow = (const short8*)(u + (size_t)node * CIN);
#pragma unroll
    for (int kk = 0; kk < 4; ++kk) a1[mt][kk] = urow[kk * 4 + lg];
  }

  // ---- mm1 ----
  const short8* W1f = (const short8*)W1P;
  for (int nt = 0; nt < 16; ++nt) {
    short8 bfr[4];
#pragma unroll
    for (int kk = 0; kk < 4; ++kk) bfr[kk] = W1f[(kk * 16 + nt) * 64 + l];
    float bb = b1[nt * 16 + ln];
#pragma unroll
    for (int mt = 0; mt < 2; ++mt) {
      float4v c = {0.f, 0.f, 0.f, 0.f};
#pragma unroll
      for (int kk = 0; kk < 4; ++kk)
        c = __builtin_amdgcn_mfma_f32_16x16x32_bf16(a1[mt][kk], bfr[kk], c, 0, 0, 0);
      // C: row = lg*4+r, col = nt*16+ln
#pragma unroll
      for (int r = 0; r < 4; ++r) {
        float h = fmaxf(c[r] + bb, 0.f);
        hS[w * 32 + mt * 16 + lg * 4 + r][nt * 16 + ln] = f2bf(h);
      }
    }
  }
  __syncthreads();  // intra-wave dependency only, but cheap insurance

  // ---- mm2 ----
  const short8* W2f = (const short8*)W2P;
  float4v o2[2][3];
#pragma unroll
  for (int mt = 0; mt < 2; ++mt)
#pragma unroll
    for (int nt2 = 0; nt2 < 3; ++nt2) o2[mt][nt2] = (float4v){0.f, 0.f, 0.f, 0.f};
  for (int kk2 = 0; kk2 < 8; ++kk2) {
    short8 af[2];
#pragma unroll
    for (int mt = 0; mt < 2; ++mt)
      af[mt] = *(const short8*)&hS[w * 32 + mt * 16 + ln][kk2 * 32 + lg * 8];
    short8 bf0 = W2f[(kk2 * 3 + 0) * 64 + l];
    short8 bf1 = W2f[(kk2 * 3 + 1) * 64 + l];
    short8 bf2 = W2f[(kk2 * 3 + 2) * 64 + l];
#pragma unroll
    for (int mt = 0; mt < 2; ++mt) {
      o2[mt][0] = __builtin_amdgcn_mfma_f32_16x16x32_bf16(af[mt], bf0, o2[mt][0], 0, 0, 0);
      o2[mt][1] = __builtin_amdgcn_mfma_f32_16x16x32_bf16(af[mt], bf1, o2[mt][1], 0, 0, 0);
      o2[mt][2] = __builtin_amdgcn_mfma_f32_16x16x32_bf16(af[mt], bf2, o2[mt][2], 0, 0, 0);
    }
  }

  // ---- log_softmax + store. C: row = lg*4+r, col = nt2*16+ln ----
  float b2v0 = b2[ln];
  float b2v1 = b2[16 + ln];
  bool v2 = (ln < 8);
  float b2v2 = v2 ? b2[32 + ln] : 0.f;
#pragma unroll
  for (int mt = 0; mt < 2; ++mt) {
#pragma unroll
    for (int r = 0; r < 4; ++r) {
      float x0 = o2[mt][0][r] + b2v0;
      float x1 = o2[mt][1][r] + b2v1;
      float x2 = v2 ? (o2[mt][2][r] + b2v2) : -INFINITY;
      float m = fmaxf(fmaxf(x0, x1), x2);
#pragma unroll
      for (int s = 1; s < 16; s <<= 1) m = fmaxf(m, __shfl_xor(m, s, 64));
      float es = __expf(x0 - m) + __expf(x1 - m) + (v2 ? __expf(x2 - m) : 0.f);
#pragma unroll
      for (int s = 1; s < 16; s <<= 1) es += __shfl_xor(es, s, 64);
      float lse = m + __logf(es);
      int node = node0 + w * 32 + mt * 16 + lg * 4 + r;
      if (node < n) {
        out[(size_t)node * COUT + ln] = x0 - lse;
        out[(size_t)node * COUT + 16 + ln] = x1 - lse;
        if (v2) out[(size_t)node * COUT + 32 + ln] = x2 - lse;
      }
    }
  }
}

// ---------------- launch ----------------

extern "C" void kernel_launch(void* const* d_in, const int* in_sizes, int n_in,
                              void* d_out, int out_size, void* d_ws, size_t ws_size,
                              hipStream_t stream) {
  const float* x = (const float*)d_in[0];
  const int* ei = (const int*)d_in[1];
  const float* W1 = (const float*)d_in[3];
  const float* b1 = (const float*)d_in[4];
  const float* W2 = (const float*)d_in[5];
  const float* b2 = (const float*)d_in[6];
  float* out = (float*)d_out;

  int N = in_sizes[0] / CIN;
  int E = in_sizes[1] / 2;
  const int* src = ei;
  const int* dst = ei + E;

  char* ws = (char*)d_ws;
  size_t off = 0;
  auto walloc = [&](size_t bytes) -> void* {
    void* p = ws + off;
    off += (bytes + 255) & ~(size_t)255;
    return p;
  };
  int* cnt = (int*)walloc((size_t)N * 4);
  int* rowptr = (int*)walloc(((size_t)N + 1) * 4);
  int* cursor = (int*)walloc((size_t)N * 4);
  int* bsum = (int*)walloc(1024 * 4);
  int* cols = (int*)walloc((size_t)E * 4);
  u16* W1P = (u16*)walloc((size_t)4 * 16 * 64 * 8 * 2);
  u16* W2P = (u16*)walloc((size_t)8 * 3 * 64 * 8 * 2);
  u16* xb = (u16*)walloc((size_t)N * CIN * 2);
  u16* u0 = (u16*)walloc((size_t)N * CIN * 2);
  u16* u1 = (u16*)walloc((size_t)N * CIN * 2);
  (void)ws_size; (void)n_in; (void)out_size;

  // CSR build (counting sort by src)
  hipMemsetAsync(cnt, 0, (size_t)N * 4, stream);
  hist_kernel<<<2048, 256, 0, stream>>>(src, cnt, E);
  int nchunks = (N + SCAN_CHUNK - 1) / SCAN_CHUNK;
  chunk_sum_kernel<<<nchunks, 256, 0, stream>>>(cnt, bsum, N);
  bsum_scan_kernel<<<1, 64, 0, stream>>>(bsum, nchunks);
  chunk_scan_kernel<<<nchunks, 256, 0, stream>>>(cnt, bsum, rowptr, N);
  hipMemcpyAsync(cursor, rowptr, (size_t)N * 4, hipMemcpyDeviceToDevice, stream);
  scatter_kernel<<<2048, 256, 0, stream>>>(src, dst, cursor, cols, E);

  // prep
  cvt_bf16_kernel<<<(N * CIN / 4 + 255) / 256, 256, 0, stream>>>(x, xb, N * CIN / 4);
  pack_w1_kernel<<<(4 * 16 * 64 * 8 + 255) / 256, 256, 0, stream>>>(W1, W1P);
  pack_w2_kernel<<<(8 * 3 * 64 * 8 + 255) / 256, 256, 0, stream>>>(W2, W2P);

  // Horner PPR: u <- x + 0.95 * P u  (10 times); 0.05 folded into W1P
  const u16* uin = xb;
  u16* ubufs[2] = {u0, u1};
  for (int k = 0; k < KPROP; ++k) {
    u16* uout = ubufs[k & 1];
    prop_bf16_kernel<<<(N + 3) / 4, 256, 0, stream>>>(uin, xb, uout, rowptr, cols, N);
    uin = uout;
  }

  mlp_mfma_kernel<<<(N + 127) / 128, 256, 0, stream>>>(uin, W1P, b1, W2P, b2, out, N);
}

// Round 3
// 1633.904 us; speedup vs baseline: 1.9171x; 1.0715x over previous
//
#include <hip/hip_runtime.h>
#include <math.h>

typedef unsigned int uint32;
typedef unsigned short u16;
typedef __attribute__((ext_vector_type(8))) short short8;
typedef __attribute__((ext_vector_type(4))) float float4v;

#define CIN 128
#define HID 256
#define COUT 40
#define KPROP 10
#define ONE_MINUS_ALPHA 0.95f
#define PPR_ALPHA 0.05f
#define SCAN_CHUNK 1024

__device__ inline u16 f2bf(float f) {
  uint32 u = __float_as_uint(f);
  u += 0x7fffu + ((u >> 16) & 1u);
  return (u16)(u >> 16);
}
__device__ inline float bflo(uint32 w) { return __uint_as_float(w << 16); }
__device__ inline float bfhi(uint32 w) { return __uint_as_float(w & 0xffff0000u); }

// ---------------- CSR build ----------------

__global__ void hist_kernel(const int* __restrict__ src, int* __restrict__ cnt, int E) {
  int i = blockIdx.x * blockDim.x + threadIdx.x;
  int stride = gridDim.x * blockDim.x;
  for (; i < E; i += stride) atomicAdd(&cnt[src[i]], 1);
}

__global__ void chunk_sum_kernel(const int* __restrict__ cnt, int* __restrict__ bsum, int n) {
  __shared__ int smem[256];
  int b = blockIdx.x, t = threadIdx.x;
  int base = b * SCAN_CHUNK;
  int s = 0;
  for (int k = 0; k < 4; ++k) {
    int idx = base + t + k * 256;
    if (idx < n) s += cnt[idx];
  }
  smem[t] = s;
  __syncthreads();
  for (int off = 128; off > 0; off >>= 1) {
    if (t < off) smem[t] += smem[t + off];
    __syncthreads();
  }
  if (t == 0) bsum[b] = smem[0];
}

// parallel one-block exclusive scan over nb <= 1024 chunk sums
__global__ void bsum_scan_kernel(int* bsum, int nb) {
  __shared__ int sm[1024];
  int t = threadIdx.x;
  int v = (t < nb) ? bsum[t] : 0;
  sm[t] = v;
  __syncthreads();
  for (int off = 1; off < 1024; off <<= 1) {
    int add = (t >= off) ? sm[t - off] : 0;
    __syncthreads();
    sm[t] += add;
    __syncthreads();
  }
  if (t < nb) bsum[t] = sm[t] - v;  // exclusive
}

__global__ void chunk_scan_kernel(const int* __restrict__ cnt, const int* __restrict__ bsum,
                                  int* __restrict__ rowptr, int n) {
  __shared__ int smem[256];
  int b = blockIdx.x, t = threadIdx.x;
  int base = b * SCAN_CHUNK + t * 4;
  int v[4];
  for (int k = 0; k < 4; ++k) v[k] = (base + k < n) ? cnt[base + k] : 0;
  int s = v[0] + v[1] + v[2] + v[3];
  smem[t] = s;
  __syncthreads();
  for (int off = 1; off < 256; off <<= 1) {
    int add = (t >= off) ? smem[t - off] : 0;
    __syncthreads();
    smem[t] += add;
    __syncthreads();
  }
  int run = bsum[b] + smem[t] - s;
  for (int k = 0; k < 4; ++k) {
    run += v[k];
    if (base + k < n) rowptr[base + k + 1] = run;
  }
  if (b == 0 && t == 0) rowptr[0] = 0;
}

__global__ void scatter_kernel(const int* __restrict__ src, const int* __restrict__ dst,
                               int* __restrict__ cursor, int* __restrict__ cols, int E) {
  int i = blockIdx.x * blockDim.x + threadIdx.x;
  int stride = gridDim.x * blockDim.x;
  for (; i < E; i += stride) {
    int pos = atomicAdd(&cursor[src[i]], 1);
    cols[pos] = dst[i];
  }
}

// ---------------- prep: casts + weight packing ----------------

__global__ void cvt_bf16_kernel(const float* __restrict__ in, u16* __restrict__ out, int n4) {
  int i = blockIdx.x * blockDim.x + threadIdx.x;
  if (i < n4) {
    float4 v = ((const float4*)in)[i];
    uint2 p;
    p.x = (uint32)f2bf(v.x) | ((uint32)f2bf(v.y) << 16);
    p.y = (uint32)f2bf(v.z) | ((uint32)f2bf(v.w) << 16);
    ((uint2*)out)[i] = p;
  }
}

// W1P: B-fragment packed, 0.05 folded in. idx = ((kk*16+nt)*64+l)*8+j8
__global__ void pack_w1_kernel(const float* __restrict__ W1, u16* __restrict__ W1P) {
  int idx = blockIdx.x * blockDim.x + threadIdx.x;
  if (idx >= 4 * 16 * 64 * 8) return;
  int j8 = idx & 7;
  int l = (idx >> 3) & 63;
  int nt = (idx >> 9) & 15;
  int kk = idx >> 13;
  int k = kk * 32 + (l >> 4) * 8 + j8;
  int nn = nt * 16 + (l & 15);
  W1P[idx] = f2bf(PPR_ALPHA * W1[nn * CIN + k]);
}

// W2P: idx = ((kk2*3+nt2)*64+l)*8+j8
__global__ void pack_w2_kernel(const float* __restrict__ W2, u16* __restrict__ W2P) {
  int idx = blockIdx.x * blockDim.x + threadIdx.x;
  if (idx >= 8 * 3 * 64 * 8) return;
  int j8 = idx & 7;
  int l = (idx >> 3) & 63;
  int nt2 = (idx >> 9) % 3;
  int kk2 = (idx >> 9) / 3;
  int k = kk2 * 32 + (l >> 4) * 8 + j8;
  int o = nt2 * 16 + (l & 15);
  W2P[idx] = (o < COUT) ? f2bf(W2[o * HID + k]) : (u16)0;
}

// ---------------- propagation (bf16, wide gather) ----------------
// wave per node. Lane split: eg = lane>>4 (edge group 0..3), ch = lane&15
// (channel quad: 8 channels = 16 B). Each wave-load moves 4 rows x 256 B.
// Per-group partials combined via 2 shfl_xor rounds per node.

__global__ __launch_bounds__(256) void prop_bf16_kernel(
    const u16* __restrict__ uin, const u16* __restrict__ xb, u16* __restrict__ uout,
    const int* __restrict__ rowptr, const int* __restrict__ cols, int n) {
  int wid = threadIdx.x >> 6;
  int lane = threadIdx.x & 63;
  int node = blockIdx.x * 4 + wid;
  if (node >= n) return;
  int eg = lane >> 4;
  int ch = lane & 15;
  int start = rowptr[node], end = rowptr[node + 1];
  const uint4* uw4 = (const uint4*)uin;

  float acc[8];
  if (eg == 0) {  // self-loop contribution, counted once
    uint4 s = uw4[(size_t)node * 16 + ch];
    acc[0] = bflo(s.x); acc[1] = bfhi(s.x);
    acc[2] = bflo(s.y); acc[3] = bfhi(s.y);
    acc[4] = bflo(s.z); acc[5] = bfhi(s.z);
    acc[6] = bflo(s.w); acc[7] = bfhi(s.w);
  } else {
#pragma unroll
    for (int j = 0; j < 8; ++j) acc[j] = 0.f;
  }

  int e = start;
  for (; e + 8 <= end; e += 8) {
    int d0 = cols[e + eg];
    int d1 = cols[e + 4 + eg];
    uint4 w0 = uw4[(size_t)d0 * 16 + ch];
    uint4 w1 = uw4[(size_t)d1 * 16 + ch];
    acc[0] += bflo(w0.x); acc[1] += bfhi(w0.x);
    acc[2] += bflo(w0.y); acc[3] += bfhi(w0.y);
    acc[4] += bflo(w0.z); acc[5] += bfhi(w0.z);
    acc[6] += bflo(w0.w); acc[7] += bfhi(w0.w);
    acc[0] += bflo(w1.x); acc[1] += bfhi(w1.x);
    acc[2] += bflo(w1.y); acc[3] += bfhi(w1.y);
    acc[4] += bflo(w1.z); acc[5] += bfhi(w1.z);
    acc[6] += bflo(w1.w); acc[7] += bfhi(w1.w);
  }
  for (; e + 4 <= end; e += 4) {
    int d0 = cols[e + eg];
    uint4 w0 = uw4[(size_t)d0 * 16 + ch];
    acc[0] += bflo(w0.x); acc[1] += bfhi(w0.x);
    acc[2] += bflo(w0.y); acc[3] += bfhi(w0.y);
    acc[4] += bflo(w0.z); acc[5] += bfhi(w0.z);
    acc[6] += bflo(w0.w); acc[7] += bfhi(w0.w);
  }
  int rem = end - e;
  if (eg < rem) {
    int d0 = cols[e + eg];
    uint4 w0 = uw4[(size_t)d0 * 16 + ch];
    acc[0] += bflo(w0.x); acc[1] += bfhi(w0.x);
    acc[2] += bflo(w0.y); acc[3] += bfhi(w0.y);
    acc[4] += bflo(w0.z); acc[5] += bfhi(w0.z);
    acc[6] += bflo(w0.w); acc[7] += bfhi(w0.w);
  }

  // combine the 4 edge-groups (channels identical across groups)
#pragma unroll
  for (int j = 0; j < 8; ++j) acc[j] += __shfl_xor(acc[j], 16, 64);
#pragma unroll
  for (int j = 0; j < 8; ++j) acc[j] += __shfl_xor(acc[j], 32, 64);

  if (eg == 0) {
    float c = ONE_MINUS_ALPHA / (float)(end - start + 1);
    uint4 xw = ((const uint4*)xb)[(size_t)node * 16 + ch];
    uint4 r;
    r.x = (uint32)f2bf(bflo(xw.x) + c * acc[0]) | ((uint32)f2bf(bfhi(xw.x) + c * acc[1]) << 16);
    r.y = (uint32)f2bf(bflo(xw.y) + c * acc[2]) | ((uint32)f2bf(bfhi(xw.y) + c * acc[3]) << 16);
    r.z = (uint32)f2bf(bflo(xw.z) + c * acc[4]) | ((uint32)f2bf(bfhi(xw.z) + c * acc[5]) << 16);
    r.w = (uint32)f2bf(bflo(xw.w) + c * acc[6]) | ((uint32)f2bf(bfhi(xw.w) + c * acc[7]) << 16);
    ((uint4*)uout)[(size_t)node * 16 + ch] = r;
  }
}

// ---------------- fused MFMA MLP + log_softmax ----------------

#define HPAD 264

__global__ __launch_bounds__(256, 2) void mlp_mfma_kernel(
    const u16* __restrict__ u, const u16* __restrict__ W1P, const float* __restrict__ b1,
    const u16* __restrict__ W2P, const float* __restrict__ b2,
    float* __restrict__ out, int n) {
  __shared__ __align__(16) u16 hS[128][HPAD];

  int t = threadIdx.x;
  int w = t >> 6, l = t & 63;
  int lg = l >> 4;
  int ln = l & 15;
  int node0 = blockIdx.x * 128;

  short8 a1[2][4];
#pragma unroll
  for (int mt = 0; mt < 2; ++mt) {
    int node = node0 + w * 32 + mt * 16 + ln;
    if (node >= n) node = n - 1;
    const short8* urow = (const short8*)(u + (size_t)node * CIN);
#pragma unroll
    for (int kk = 0; kk < 4; ++kk) a1[mt][kk] = urow[kk * 4 + lg];
  }

  const short8* W1f = (const short8*)W1P;
  for (int nt = 0; nt < 16; ++nt) {
    short8 bfr[4];
#pragma unroll
    for (int kk = 0; kk < 4; ++kk) bfr[kk] = W1f[(kk * 16 + nt) * 64 + l];
    float bb = b1[nt * 16 + ln];
#pragma unroll
    for (int mt = 0; mt < 2; ++mt) {
      float4v c = {0.f, 0.f, 0.f, 0.f};
#pragma unroll
      for (int kk = 0; kk < 4; ++kk)
        c = __builtin_amdgcn_mfma_f32_16x16x32_bf16(a1[mt][kk], bfr[kk], c, 0, 0, 0);
#pragma unroll
      for (int r = 0; r < 4; ++r) {
        float h = fmaxf(c[r] + bb, 0.f);
        hS[w * 32 + mt * 16 + lg * 4 + r][nt * 16 + ln] = f2bf(h);
      }
    }
  }
  __syncthreads();

  const short8* W2f = (const short8*)W2P;
  float4v o2[2][3];
#pragma unroll
  for (int mt = 0; mt < 2; ++mt)
#pragma unroll
    for (int nt2 = 0; nt2 < 3; ++nt2) o2[mt][nt2] = (float4v){0.f, 0.f, 0.f, 0.f};
  for (int kk2 = 0; kk2 < 8; ++kk2) {
    short8 af[2];
#pragma unroll
    for (int mt = 0; mt < 2; ++mt)
      af[mt] = *(const short8*)&hS[w * 32 + mt * 16 + ln][kk2 * 32 + lg * 8];
    short8 bf0 = W2f[(kk2 * 3 + 0) * 64 + l];
    short8 bf1 = W2f[(kk2 * 3 + 1) * 64 + l];
    short8 bf2 = W2f[(kk2 * 3 + 2) * 64 + l];
#pragma unroll
    for (int mt = 0; mt < 2; ++mt) {
      o2[mt][0] = __builtin_amdgcn_mfma_f32_16x16x32_bf16(af[mt], bf0, o2[mt][0], 0, 0, 0);
      o2[mt][1] = __builtin_amdgcn_mfma_f32_16x16x32_bf16(af[mt], bf1, o2[mt][1], 0, 0, 0);
      o2[mt][2] = __builtin_amdgcn_mfma_f32_16x16x32_bf16(af[mt], bf2, o2[mt][2], 0, 0, 0);
    }
  }

  float b2v0 = b2[ln];
  float b2v1 = b2[16 + ln];
  bool v2 = (ln < 8);
  float b2v2 = v2 ? b2[32 + ln] : 0.f;
#pragma unroll
  for (int mt = 0; mt < 2; ++mt) {
#pragma unroll
    for (int r = 0; r < 4; ++r) {
      float x0 = o2[mt][0][r] + b2v0;
      float x1 = o2[mt][1][r] + b2v1;
      float x2 = v2 ? (o2[mt][2][r] + b2v2) : -INFINITY;
      float m = fmaxf(fmaxf(x0, x1), x2);
#pragma unroll
      for (int s = 1; s < 16; s <<= 1) m = fmaxf(m, __shfl_xor(m, s, 64));
      float es = __expf(x0 - m) + __expf(x1 - m) + (v2 ? __expf(x2 - m) : 0.f);
#pragma unroll
      for (int s = 1; s < 16; s <<= 1) es += __shfl_xor(es, s, 64);
      float lse = m + __logf(es);
      int node = node0 + w * 32 + mt * 16 + lg * 4 + r;
      if (node < n) {
        out[(size_t)node * COUT + ln] = x0 - lse;
        out[(size_t)node * COUT + 16 + ln] = x1 - lse;
        if (v2) out[(size_t)node * COUT + 32 + ln] = x2 - lse;
      }
    }
  }
}

// ---------------- launch ----------------

extern "C" void kernel_launch(void* const* d_in, const int* in_sizes, int n_in,
                              void* d_out, int out_size, void* d_ws, size_t ws_size,
                              hipStream_t stream) {
  const float* x = (const float*)d_in[0];
  const int* ei = (const int*)d_in[1];
  const float* W1 = (const float*)d_in[3];
  const float* b1 = (const float*)d_in[4];
  const float* W2 = (const float*)d_in[5];
  const float* b2 = (const float*)d_in[6];
  float* out = (float*)d_out;

  int N = in_sizes[0] / CIN;
  int E = in_sizes[1] / 2;
  const int* src = ei;
  const int* dst = ei + E;

  char* ws = (char*)d_ws;
  size_t off = 0;
  auto walloc = [&](size_t bytes) -> void* {
    void* p = ws + off;
    off += (bytes + 255) & ~(size_t)255;
    return p;
  };
  int* cnt = (int*)walloc((size_t)N * 4);
  int* rowptr = (int*)walloc(((size_t)N + 1) * 4);
  int* cursor = (int*)walloc((size_t)N * 4);
  int* bsum = (int*)walloc(1024 * 4);
  int* cols = (int*)walloc((size_t)E * 4);
  u16* W1P = (u16*)walloc((size_t)4 * 16 * 64 * 8 * 2);
  u16* W2P = (u16*)walloc((size_t)8 * 3 * 64 * 8 * 2);
  u16* xb = (u16*)walloc((size_t)N * CIN * 2);
  u16* u0 = (u16*)walloc((size_t)N * CIN * 2);
  u16* u1 = (u16*)walloc((size_t)N * CIN * 2);
  (void)ws_size; (void)n_in; (void)out_size;

  // CSR build (counting sort by src)
  hipMemsetAsync(cnt, 0, (size_t)N * 4, stream);
  hist_kernel<<<2048, 256, 0, stream>>>(src, cnt, E);
  int nchunks = (N + SCAN_CHUNK - 1) / SCAN_CHUNK;
  chunk_sum_kernel<<<nchunks, 256, 0, stream>>>(cnt, bsum, N);
  bsum_scan_kernel<<<1, 1024, 0, stream>>>(bsum, nchunks);
  chunk_scan_kernel<<<nchunks, 256, 0, stream>>>(cnt, bsum, rowptr, N);
  hipMemcpyAsync(cursor, rowptr, (size_t)N * 4, hipMemcpyDeviceToDevice, stream);
  scatter_kernel<<<2048, 256, 0, stream>>>(src, dst, cursor, cols, E);

  // prep
  cvt_bf16_kernel<<<(N * CIN / 4 + 255) / 256, 256, 0, stream>>>(x, xb, N * CIN / 4);
  pack_w1_kernel<<<(4 * 16 * 64 * 8 + 255) / 256, 256, 0, stream>>>(W1, W1P);
  pack_w2_kernel<<<(8 * 3 * 64 * 8 + 255) / 256, 256, 0, stream>>>(W2, W2P);

  // Horner PPR: u <- x + 0.95 * P u  (10 times); 0.05 folded into W1P
  const u16* uin = xb;
  u16* ubufs[2] = {u0, u1};
  for (int k = 0; k < KPROP; ++k) {
    u16* uout = ubufs[k & 1];
    prop_bf16_kernel<<<(N + 3) / 4, 256, 0, stream>>>(uin, xb, uout, rowptr, cols, N);
    uin = uout;
  }

  mlp_mfma_kernel<<<(N + 127) / 128, 256, 0, stream>>>(uin, W1P, b1, W2P, b2, out, N);
}